// Round 19
// baseline (189.062 us; speedup 1.0000x reference)
//
#include <hip/hip_runtime.h>

#define VOCAB 10000
#define EMB   16
#define HID   32
#define BATCH 4096
#define TLEN  512

typedef _Float16 f16x2 __attribute__((ext_vector_type(2)));

#define TWO_LOG2E 2.8853900817779268f   /* 2*log2(e) */

// ---------------------------------------------------------------------------
// Kernel 1: P'[v][j] = (b[j] + sum_e emb[v][e]*Wx[e][j]) * 2log2e
// ---------------------------------------------------------------------------
__global__ __launch_bounds__(256) void rnn_proj(
    const float* __restrict__ emb, const float* __restrict__ Wx,
    const float* __restrict__ bias, float* __restrict__ P)
{
    int tid = blockIdx.x * 256 + threadIdx.x;
    if (tid >= VOCAB * HID) return;
    int v = tid >> 5;
    int j = tid & 31;
    float acc = bias[j];
    const float* ev = emb + v * EMB;
#pragma unroll
    for (int e = 0; e < EMB; ++e) {
        acc = fmaf(ev[e], Wx[e * HID + j], acc);
    }
    P[tid] = acc * TWO_LOG2E;
}

// ---------------------------------------------------------------------------
// Kernel 2: bpermute scan. r16 structure (wave = 2 batches x 32 j-lanes,
// full 32-MAC dot per lane via 16 v_dot2_f32_f16) but h broadcast via
// ds_bpermute instead of LDS store/load:
//   r18 showed the ~400cy/step chain is the ds_write -> ds_read round-trip
//   (2 serial LDS latency legs). bpermute is the LDS crossbar WITHOUT the
//   memory round-trip: tanh -> DPP xor1 -> cvt_pkrtz packs {h_2m,h_2m+1}
//   on even lanes; 16 independent bpermutes pull all pairs (one latency
//   leg, all in flight). Pair order matches r16's wh2[] exactly.
// No LDS array at all. Keeps: 2log2e fold (exp2 direct), 2 accumulators,
// quad unroll, int4 tokens, P prefetch one quad ahead, pinned weights,
// waves_per_eu(2,2).
// ---------------------------------------------------------------------------
__global__ __launch_bounds__(256)
__attribute__((amdgpu_waves_per_eu(2, 2)))
void rnn_scan(
    const int*   __restrict__ x,   const float* __restrict__ P,
    const float* __restrict__ Wh,  const float* __restrict__ Wd,
    const float* __restrict__ bd,  float* __restrict__ out)
{
    const int lane = threadIdx.x & 63;
    const int wave = threadIdx.x >> 6;
    const int half = lane >> 5;
    const int j    = lane & 31;
    const int b    = blockIdx.x * 8 + wave * 2 + half;

    // Wh column j, pre-scaled by 2log2e, as fp16 pairs
    f16x2 wh2[16];
#pragma unroll
    for (int m = 0; m < 16; ++m) {
        wh2[m] = (f16x2){ (_Float16)(Wh[(2 * m + 0) * HID + j] * TWO_LOG2E),
                          (_Float16)(Wh[(2 * m + 1) * HID + j] * TWO_LOG2E) };
    }
#pragma unroll
    for (int m = 0; m < 16; ++m) asm("" : "+v"(wh2[m]));  // remat-proof

    const int* xb = x + b * TLEN;

    // pipeline prologue: tokens for quads 0/1, P' for quad 0
    int4 tq_cur = *(const int4*)(xb);
    int4 tq_nxt = *(const int4*)(xb + 4);
    float pc0 = P[tq_cur.x * HID + j];
    float pc1 = P[tq_cur.y * HID + j];
    float pc2 = P[tq_cur.z * HID + j];
    float pc3 = P[tq_cur.w * HID + j];

    float hj = 0.0f;
    int   pk = 0;                               // packed pair source; h0 = 0
    const int bpbase = half << 7;               // batch-half lane window (x4 B)

#define BC(I)  __builtin_bit_cast(f16x2, I)
#define STEP(PV)                                                              \
    {                                                                         \
        int p0  = __builtin_amdgcn_ds_bpermute(bpbase +   0, pk);             \
        int p1  = __builtin_amdgcn_ds_bpermute(bpbase +   8, pk);             \
        int p2  = __builtin_amdgcn_ds_bpermute(bpbase +  16, pk);             \
        int p3  = __builtin_amdgcn_ds_bpermute(bpbase +  24, pk);             \
        int p4  = __builtin_amdgcn_ds_bpermute(bpbase +  32, pk);             \
        int p5  = __builtin_amdgcn_ds_bpermute(bpbase +  40, pk);             \
        int p6  = __builtin_amdgcn_ds_bpermute(bpbase +  48, pk);             \
        int p7  = __builtin_amdgcn_ds_bpermute(bpbase +  56, pk);             \
        int p8  = __builtin_amdgcn_ds_bpermute(bpbase +  64, pk);             \
        int p9  = __builtin_amdgcn_ds_bpermute(bpbase +  72, pk);             \
        int p10 = __builtin_amdgcn_ds_bpermute(bpbase +  80, pk);             \
        int p11 = __builtin_amdgcn_ds_bpermute(bpbase +  88, pk);             \
        int p12 = __builtin_amdgcn_ds_bpermute(bpbase +  96, pk);             \
        int p13 = __builtin_amdgcn_ds_bpermute(bpbase + 104, pk);             \
        int p14 = __builtin_amdgcn_ds_bpermute(bpbase + 112, pk);             \
        int p15 = __builtin_amdgcn_ds_bpermute(bpbase + 120, pk);             \
        float a0 = (PV), a1 = 0.f;                                            \
        a0 = __builtin_amdgcn_fdot2(BC(p0),  wh2[0],  a0, false);             \
        a1 = __builtin_amdgcn_fdot2(BC(p1),  wh2[1],  a1, false);             \
        a0 = __builtin_amdgcn_fdot2(BC(p2),  wh2[2],  a0, false);             \
        a1 = __builtin_amdgcn_fdot2(BC(p3),  wh2[3],  a1, false);             \
        a0 = __builtin_amdgcn_fdot2(BC(p4),  wh2[4],  a0, false);             \
        a1 = __builtin_amdgcn_fdot2(BC(p5),  wh2[5],  a1, false);             \
        a0 = __builtin_amdgcn_fdot2(BC(p6),  wh2[6],  a0, false);             \
        a1 = __builtin_amdgcn_fdot2(BC(p7),  wh2[7],  a1, false);             \
        a0 = __builtin_amdgcn_fdot2(BC(p8),  wh2[8],  a0, false);             \
        a1 = __builtin_amdgcn_fdot2(BC(p9),  wh2[9],  a1, false);             \
        a0 = __builtin_amdgcn_fdot2(BC(p10), wh2[10], a0, false);             \
        a1 = __builtin_amdgcn_fdot2(BC(p11), wh2[11], a1, false);             \
        a0 = __builtin_amdgcn_fdot2(BC(p12), wh2[12], a0, false);             \
        a1 = __builtin_amdgcn_fdot2(BC(p13), wh2[13], a1, false);             \
        a0 = __builtin_amdgcn_fdot2(BC(p14), wh2[14], a0, false);             \
        a1 = __builtin_amdgcn_fdot2(BC(p15), wh2[15], a1, false);             \
        float z  = a0 + a1;                     /* already x 2log2e */        \
        float e2 = __builtin_amdgcn_exp2f(z);   /* = e^{2z_true} */           \
        float r  = __builtin_amdgcn_rcpf(e2 + 1.0f);                          \
        hj = fmaf(-2.0f, r, 1.0f);                                            \
        /* pack pair {h_2m, h_2m+1} on even lanes: DPP xor1 + cvt_pkrtz */    \
        int hp = __builtin_amdgcn_update_dpp(                                 \
            0, __builtin_bit_cast(int, hj), 0xB1 /*quad_perm[1,0,3,2]*/,      \
            0xf, 0xf, true);                                                  \
        pk = __builtin_bit_cast(int, __builtin_amdgcn_cvt_pkrtz(              \
            hj, __builtin_bit_cast(float, hp)));                              \
    }

    const int NQ = TLEN / 4;                    // 128 quads, exact

    for (int k = 0; k < NQ; ++k) {
        // prefetch P' for quad k+1 (tokens already resident in tq_nxt)
        float pn0 = P[tq_nxt.x * HID + j];
        float pn1 = P[tq_nxt.y * HID + j];
        float pn2 = P[tq_nxt.z * HID + j];
        float pn3 = P[tq_nxt.w * HID + j];
        // prefetch token quad k+2 (clamped; tail values unused)
        int  q2i = (k + 2 < NQ) ? (k + 2) : (NQ - 1);
        int4 tq2 = *(const int4*)(xb + 4 * q2i);

        STEP(pc0)
        STEP(pc1)
        STEP(pc2)
        STEP(pc3)

        pc0 = pn0; pc1 = pn1; pc2 = pn2; pc3 = pn3;
        tq_nxt = tq2;
    }
#undef STEP
#undef BC

    // out[b] = sigmoid(sum_j h_j * Wd[j] + bd)
    float s = hj * Wd[j];
#pragma unroll
    for (int off = 16; off > 0; off >>= 1)
        s += __shfl_xor(s, off, 32);            // reduce within 32-lane half
    if (j == 0) {
        float logit = s + bd[0];
        out[b] = 1.0f / (1.0f + __expf(-logit)); // fp32 output
    }
}

// ---------------------------------------------------------------------------
extern "C" void kernel_launch(void* const* d_in, const int* in_sizes, int n_in,
                              void* d_out, int out_size, void* d_ws, size_t ws_size,
                              hipStream_t stream)
{
    const int*   x   = (const int*)  d_in[0];
    const float* emb = (const float*)d_in[1];
    const float* Wx  = (const float*)d_in[2];
    const float* Wh  = (const float*)d_in[3];
    const float* bia = (const float*)d_in[4];
    const float* Wd  = (const float*)d_in[5];
    const float* bd  = (const float*)d_in[6];
    float* out = (float*)d_out;

    float* P = (float*)d_ws;                    // VOCAB*HID*4 = 1.28 MB (pre-scaled)

    rnn_proj<<<(VOCAB * HID + 255) / 256, 256, 0, stream>>>(emb, Wx, bia, P);
    rnn_scan<<<BATCH / 8, 256, 0, stream>>>(x, P, Wh, Wd, bd, out);
}

// Round 20
// 113.911 us; speedup vs baseline: 1.6597x; 1.6597x over previous
//
#include <hip/hip_runtime.h>

#define VOCAB 10000
#define EMB   16
#define HID   32
#define BATCH 4096
#define TLEN  512

typedef _Float16 f16x4 __attribute__((ext_vector_type(4)));
typedef _Float16 f16x2 __attribute__((ext_vector_type(2)));
typedef float    f32x4 __attribute__((ext_vector_type(4)));

#define TWO_LOG2E 2.8853900817779268f   /* 2*log2(e) */

// ---------------------------------------------------------------------------
// Kernel 1: P'[v][j] = (b[j] + sum_e emb[v][e]*Wx[e][j]) * 2log2e
// (scan feeds exp2 directly; MFMA A-fragments carry the same scale)
// ---------------------------------------------------------------------------
__global__ __launch_bounds__(256) void rnn_proj(
    const float* __restrict__ emb, const float* __restrict__ Wx,
    const float* __restrict__ bias, float* __restrict__ P)
{
    int tid = blockIdx.x * 256 + threadIdx.x;
    if (tid >= VOCAB * HID) return;
    int v = tid >> 5;
    int j = tid & 31;
    float acc = bias[j];
    const float* ev = emb + v * EMB;
#pragma unroll
    for (int e = 0; e < EMB; ++e) {
        acc = fmaf(ev[e], Wx[e * HID + j], acc);
    }
    P[tid] = acc * TWO_LOG2E;
}

// ---------------------------------------------------------------------------
// Kernel 2: self-feeding MFMA scan — r15's chain surgery, correctly
// register-budgeted this time.
//   - The VALU lineage is chain-bound at C~400cy (LDS write->read round
//     trip); its floor 512*C = 86us is measured (r16/r18). MFMA form
//     deletes the round trip: D frag == B frag (verified r13), recurrence
//     never leaves registers.
//   - r13's C=520 chained TWO mfma latencies (z0 = mfma(A01,B1, mfma(A00,
//     B0,P))); here the 4 MFMAs are INDEPENDENT (C=P / C=0) + f32x4 add:
//     one mfma latency on the chain, tanh(z0) overlaps z1 completion.
//   - r15's failure was dropping waves_per_eu(1,1): VGPR collapsed 132->36
//     and the 16-reg P-prefetch pipeline died. Kept here + A frags pinned.
//   - 2log2e folded into P' and A: z arrives pre-scaled, exp2 direct.
// One wave = 16 batches, 256 blocks x 64 thr. Occupancy is structurally
// 1 wave/CU — the play is the short chain, not TLP.
// ---------------------------------------------------------------------------
__global__ __launch_bounds__(64)
__attribute__((amdgpu_waves_per_eu(1, 1)))
void rnn_scan(
    const int*   __restrict__ x,   const float* __restrict__ P,
    const float* __restrict__ Wh,  const float* __restrict__ Wd,
    const float* __restrict__ bd,  float* __restrict__ out)
{
    const int l  = threadIdx.x & 63;
    const int bq = l & 15;                      // batch within tile / A-row j
    const int kg = l >> 4;                      // k-group: k-quad = 4*kg..+3
    const int bt = blockIdx.x * 16;             // batch tile base

    // A = Wh^T * 2log2e fragments: lane holds A[row][k] = Wh[k][row]*s
    f16x4 A00, A01, A10, A11;                   // [j-half][k-half]
#pragma unroll
    for (int r = 0; r < 4; ++r) {
        A00[r] = (_Float16)(Wh[(4 * kg + r)      * HID + bq]      * TWO_LOG2E);
        A01[r] = (_Float16)(Wh[(16 + 4 * kg + r) * HID + bq]      * TWO_LOG2E);
        A10[r] = (_Float16)(Wh[(4 * kg + r)      * HID + 16 + bq] * TWO_LOG2E);
        A11[r] = (_Float16)(Wh[(16 + 4 * kg + r) * HID + 16 + bq] * TWO_LOG2E);
    }
    asm("" : "+v"(A00), "+v"(A01), "+v"(A10), "+v"(A11));   // remat-proof

    const int*   xb = x + (bt + bq) * TLEN;     // lanes 16+ dup lanes 0-15
    const float* Pg = P + 4 * kg;               // lane's j-quad base in a P row

    // token quads
    int4 tq_cur = *(const int4*)(xb);           // steps 0..3
    int4 tq_nxt = *(const int4*)(xb + 4);       // steps 4..7

    // P' for quad 0 (prologue latency accepted once)
    f32x4 pc0a = *(const f32x4*)(Pg + tq_cur.x * HID);
    f32x4 pc0b = *(const f32x4*)(Pg + tq_cur.x * HID + 16);
    f32x4 pc1a = *(const f32x4*)(Pg + tq_cur.y * HID);
    f32x4 pc1b = *(const f32x4*)(Pg + tq_cur.y * HID + 16);
    f32x4 pc2a = *(const f32x4*)(Pg + tq_cur.z * HID);
    f32x4 pc2b = *(const f32x4*)(Pg + tq_cur.z * HID + 16);
    f32x4 pc3a = *(const f32x4*)(Pg + tq_cur.w * HID);
    f32x4 pc3b = *(const f32x4*)(Pg + tq_cur.w * HID + 16);

    f16x4 B0 = {};                              // h^T, i 0-15  (starts at 0)
    f16x4 B1 = {};                              // h^T, i 16-31
    const f32x4 ZV = {0.0f, 0.0f, 0.0f, 0.0f};

    // z arrives pre-scaled by 2log2e: tanh = 1 - 2/(exp2(z')+1)
#define TANH(Z) ({ float _e2 = __builtin_amdgcn_exp2f(Z);                     \
                   fmaf(-2.0f, __builtin_amdgcn_rcpf(_e2 + 1.0f), 1.0f); })

#define STEP(PA, PB)                                                          \
    {                                                                         \
        f32x4 z0a = __builtin_amdgcn_mfma_f32_16x16x16f16(A00, B0, (PA), 0, 0, 0); \
        f32x4 z0b = __builtin_amdgcn_mfma_f32_16x16x16f16(A01, B1, ZV,   0, 0, 0); \
        f32x4 z1a = __builtin_amdgcn_mfma_f32_16x16x16f16(A10, B0, (PB), 0, 0, 0); \
        f32x4 z1b = __builtin_amdgcn_mfma_f32_16x16x16f16(A11, B1, ZV,   0, 0, 0); \
        f32x4 z0 = z0a + z0b;                                                 \
        f32x4 z1 = z1a + z1b;                                                 \
        float t00 = TANH(z0[0]), t01 = TANH(z0[1]);                           \
        float t02 = TANH(z0[2]), t03 = TANH(z0[3]);                           \
        float t10 = TANH(z1[0]), t11 = TANH(z1[1]);                           \
        float t12 = TANH(z1[2]), t13 = TANH(z1[3]);                           \
        f16x2 q0 = __builtin_bit_cast(f16x2, __builtin_amdgcn_cvt_pkrtz(t00, t01)); \
        f16x2 q1 = __builtin_bit_cast(f16x2, __builtin_amdgcn_cvt_pkrtz(t02, t03)); \
        f16x2 q2 = __builtin_bit_cast(f16x2, __builtin_amdgcn_cvt_pkrtz(t10, t11)); \
        f16x2 q3 = __builtin_bit_cast(f16x2, __builtin_amdgcn_cvt_pkrtz(t12, t13)); \
        B0 = __builtin_shufflevector(q0, q1, 0, 1, 2, 3);                     \
        B1 = __builtin_shufflevector(q2, q3, 0, 1, 2, 3);                     \
    }

    const int NQ = TLEN / 4;                    // 128 quads, exact

    for (int k = 0; k < NQ; ++k) {
        // prefetch P' for quad k+1 (tokens already resident in tq_nxt)
        f32x4 pn0a = *(const f32x4*)(Pg + tq_nxt.x * HID);
        f32x4 pn0b = *(const f32x4*)(Pg + tq_nxt.x * HID + 16);
        f32x4 pn1a = *(const f32x4*)(Pg + tq_nxt.y * HID);
        f32x4 pn1b = *(const f32x4*)(Pg + tq_nxt.y * HID + 16);
        f32x4 pn2a = *(const f32x4*)(Pg + tq_nxt.z * HID);
        f32x4 pn2b = *(const f32x4*)(Pg + tq_nxt.z * HID + 16);
        f32x4 pn3a = *(const f32x4*)(Pg + tq_nxt.w * HID);
        f32x4 pn3b = *(const f32x4*)(Pg + tq_nxt.w * HID + 16);
        // prefetch token quad k+2 (clamped; tail values unused)
        int  q2i = (k + 2 < NQ) ? (k + 2) : (NQ - 1);
        int4 tq2 = *(const int4*)(xb + 4 * q2i);

        STEP(pc0a, pc0b)
        STEP(pc1a, pc1b)
        STEP(pc2a, pc2b)
        STEP(pc3a, pc3b)

        pc0a = pn0a; pc0b = pn0b; pc1a = pn1a; pc1b = pn1b;
        pc2a = pn2a; pc2b = pn2b; pc3a = pn3a; pc3b = pn3b;
        tq_nxt = tq2;
    }
#undef STEP
#undef TANH

    // h^T[j][b]: B0 -> j = 4*kg+r, B1 -> j = 16+4*kg+r, b = bt + (l&15)
    // out[b] = sigmoid(sum_j h[b][j] * Wd[j] + bd)
    float s = 0.0f;
#pragma unroll
    for (int r = 0; r < 4; ++r) {
        s = fmaf((float)B0[r], Wd[4 * kg + r],      s);
        s = fmaf((float)B1[r], Wd[16 + 4 * kg + r], s);
    }
    s += __shfl_xor(s, 16, 64);                 // reduce over the 4 kg-groups
    s += __shfl_xor(s, 32, 64);
    if (l < 16) {
        float logit = s + bd[0];
        out[bt + l] = 1.0f / (1.0f + __expf(-logit));
    }
}

// ---------------------------------------------------------------------------
extern "C" void kernel_launch(void* const* d_in, const int* in_sizes, int n_in,
                              void* d_out, int out_size, void* d_ws, size_t ws_size,
                              hipStream_t stream)
{
    const int*   x   = (const int*)  d_in[0];
    const float* emb = (const float*)d_in[1];
    const float* Wx  = (const float*)d_in[2];
    const float* Wh  = (const float*)d_in[3];
    const float* bia = (const float*)d_in[4];
    const float* Wd  = (const float*)d_in[5];
    const float* bd  = (const float*)d_in[6];
    float* out = (float*)d_out;

    float* P = (float*)d_ws;                    // VOCAB*HID*4 = 1.28 MB (pre-scaled)

    rnn_proj<<<(VOCAB * HID + 255) / 256, 256, 0, stream>>>(emb, Wx, bia, P);
    rnn_scan<<<BATCH / 16, 64, 0, stream>>>(x, P, Wh, Wd, bd, out);
}

// Round 21
// 84.798 us; speedup vs baseline: 2.2296x; 1.3433x over previous
//
#include <hip/hip_runtime.h>

#define VOCAB 10000
#define EMB   16
#define HID   32
#define BATCH 4096
#define TLEN  512

typedef _Float16 f16x2 __attribute__((ext_vector_type(2)));
typedef _Float16 f16x8 __attribute__((ext_vector_type(8)));

#define TWO_LOG2E 2.8853900817779268f   /* 2*log2(e) */

// ---------------------------------------------------------------------------
// Kernel 1: P'[v][j] = (b[j] + sum_e emb[v][e]*Wx[e][j]) * 2log2e
// ---------------------------------------------------------------------------
__global__ __launch_bounds__(256) void rnn_proj(
    const float* __restrict__ emb, const float* __restrict__ Wx,
    const float* __restrict__ bias, float* __restrict__ P)
{
    int tid = blockIdx.x * 256 + threadIdx.x;
    if (tid >= VOCAB * HID) return;
    int v = tid >> 5;
    int j = tid & 31;
    float acc = bias[j];
    const float* ev = emb + v * EMB;
#pragma unroll
    for (int e = 0; e < EMB; ++e) {
        acc = fmaf(ev[e], Wx[e * HID + j], acc);
    }
    P[tid] = acc * TWO_LOG2E;
}

// ---------------------------------------------------------------------------
// Kernel 2: fp16/fdot2 scan — r16 champion structure (86us/dispatch) with
// extraction-free operand feed.
//   r16's counters showed ~60 VALU instrs/wave-step vs ~29 needed; suspect:
//   shufflevector PAIR() extractions materializing as v_mov/v_perm. Here
//   each f16x8 LDS row is bit-cast to int4 and the four 32-bit components
//   feed v_dot2_f32_f16 directly — pure register aliasing, zero extraction
//   instructions, numerically bit-identical to r16.
// Wave = 2 batches x 32 j-lanes, full 32-MAC dot per lane, no shuffles, no
// barriers (wave-private LDS rows). Keeps: 2log2e fold (exp2 direct), 2
// accumulators, f16 h rows (4 ds_read_b128 broadcast), quad unroll, int4
// tokens, P prefetch one quad ahead, pinned weights, waves_per_eu(2,2).
// MFMA lineage abandoned: r13/r20 both 520cy/step (B-dep latency + trans
// ops unhideable at 1 wave/SIMD); VALU lineage floor is the LDS round-trip.
// ---------------------------------------------------------------------------
__global__ __launch_bounds__(256)
__attribute__((amdgpu_waves_per_eu(2, 2)))
void rnn_scan(
    const int*   __restrict__ x,   const float* __restrict__ P,
    const float* __restrict__ Wh,  const float* __restrict__ Wd,
    const float* __restrict__ bd,  float* __restrict__ out)
{
    __shared__ _Float16 h_lds[8][HID];          // 8 rows x 64 B

    const int lane = threadIdx.x & 63;
    const int wave = threadIdx.x >> 6;
    const int half = lane >> 5;
    const int j    = lane & 31;
    const int hb   = wave * 2 + half;           // wave-private row
    const int b    = blockIdx.x * 8 + hb;

    // Wh column j, pre-scaled by 2log2e, as fp16 pairs
    f16x2 wh2[16];
#pragma unroll
    for (int m = 0; m < 16; ++m) {
        wh2[m] = (f16x2){ (_Float16)(Wh[(2 * m + 0) * HID + j] * TWO_LOG2E),
                          (_Float16)(Wh[(2 * m + 1) * HID + j] * TWO_LOG2E) };
    }
#pragma unroll
    for (int m = 0; m < 16; ++m) asm("" : "+v"(wh2[m]));  // remat-proof

    h_lds[hb][j] = (_Float16)0.0f;              // h0 = 0 (wave-private)

    const int* xb = x + b * TLEN;

    // pipeline prologue: tokens for quads 0/1, P' for quad 0
    int4 tq_cur = *(const int4*)(xb);
    int4 tq_nxt = *(const int4*)(xb + 4);
    float pc0 = P[tq_cur.x * HID + j];
    float pc1 = P[tq_cur.y * HID + j];
    float pc2 = P[tq_cur.z * HID + j];
    float pc3 = P[tq_cur.w * HID + j];

    float hj = 0.0f;
    const f16x8* hrow = (const f16x8*)(&h_lds[hb][0]);

#define BC(I) __builtin_bit_cast(f16x2, I)
#define STEP(PV)                                                              \
    {                                                                         \
        int4 w0 = __builtin_bit_cast(int4, hrow[0]);                          \
        int4 w1 = __builtin_bit_cast(int4, hrow[1]);                          \
        int4 w2 = __builtin_bit_cast(int4, hrow[2]);                          \
        int4 w3 = __builtin_bit_cast(int4, hrow[3]);                          \
        float a0 = (PV), a1 = 0.f;                                            \
        a0 = __builtin_amdgcn_fdot2(BC(w0.x), wh2[0],  a0, false);            \
        a1 = __builtin_amdgcn_fdot2(BC(w0.y), wh2[1],  a1, false);            \
        a0 = __builtin_amdgcn_fdot2(BC(w0.z), wh2[2],  a0, false);            \
        a1 = __builtin_amdgcn_fdot2(BC(w0.w), wh2[3],  a1, false);            \
        a0 = __builtin_amdgcn_fdot2(BC(w1.x), wh2[4],  a0, false);            \
        a1 = __builtin_amdgcn_fdot2(BC(w1.y), wh2[5],  a1, false);            \
        a0 = __builtin_amdgcn_fdot2(BC(w1.z), wh2[6],  a0, false);            \
        a1 = __builtin_amdgcn_fdot2(BC(w1.w), wh2[7],  a1, false);            \
        a0 = __builtin_amdgcn_fdot2(BC(w2.x), wh2[8],  a0, false);            \
        a1 = __builtin_amdgcn_fdot2(BC(w2.y), wh2[9],  a1, false);            \
        a0 = __builtin_amdgcn_fdot2(BC(w2.z), wh2[10], a0, false);            \
        a1 = __builtin_amdgcn_fdot2(BC(w2.w), wh2[11], a1, false);            \
        a0 = __builtin_amdgcn_fdot2(BC(w3.x), wh2[12], a0, false);            \
        a1 = __builtin_amdgcn_fdot2(BC(w3.y), wh2[13], a1, false);            \
        a0 = __builtin_amdgcn_fdot2(BC(w3.z), wh2[14], a0, false);            \
        a1 = __builtin_amdgcn_fdot2(BC(w3.w), wh2[15], a1, false);            \
        float z  = a0 + a1;                     /* already x 2log2e */        \
        float e2 = __builtin_amdgcn_exp2f(z);   /* = e^{2z_true} */           \
        float r  = __builtin_amdgcn_rcpf(e2 + 1.0f);                          \
        hj = fmaf(-2.0f, r, 1.0f);                                            \
        h_lds[hb][j] = (_Float16)hj;                                          \
    }

    const int NQ = TLEN / 4;                    // 128 quads, exact

    for (int k = 0; k < NQ; ++k) {
        // prefetch P' for quad k+1 (tokens already resident in tq_nxt)
        float pn0 = P[tq_nxt.x * HID + j];
        float pn1 = P[tq_nxt.y * HID + j];
        float pn2 = P[tq_nxt.z * HID + j];
        float pn3 = P[tq_nxt.w * HID + j];
        // prefetch token quad k+2 (clamped; tail values unused)
        int  q2i = (k + 2 < NQ) ? (k + 2) : (NQ - 1);
        int4 tq2 = *(const int4*)(xb + 4 * q2i);

        STEP(pc0)
        STEP(pc1)
        STEP(pc2)
        STEP(pc3)

        pc0 = pn0; pc1 = pn1; pc2 = pn2; pc3 = pn3;
        tq_nxt = tq2;
    }
#undef STEP
#undef BC

    // out[b] = sigmoid(sum_j h_j * Wd[j] + bd)
    float s = hj * Wd[j];
#pragma unroll
    for (int off = 16; off > 0; off >>= 1)
        s += __shfl_xor(s, off, 32);            // reduce within 32-lane half
    if (j == 0) {
        float logit = s + bd[0];
        out[b] = 1.0f / (1.0f + __expf(-logit)); // fp32 output
    }
}

// ---------------------------------------------------------------------------
extern "C" void kernel_launch(void* const* d_in, const int* in_sizes, int n_in,
                              void* d_out, int out_size, void* d_ws, size_t ws_size,
                              hipStream_t stream)
{
    const int*   x   = (const int*)  d_in[0];
    const float* emb = (const float*)d_in[1];
    const float* Wx  = (const float*)d_in[2];
    const float* Wh  = (const float*)d_in[3];
    const float* bia = (const float*)d_in[4];
    const float* Wd  = (const float*)d_in[5];
    const float* bd  = (const float*)d_in[6];
    float* out = (float*)d_out;

    float* P = (float*)d_ws;                    // VOCAB*HID*4 = 1.28 MB (pre-scaled)

    rnn_proj<<<(VOCAB * HID + 255) / 256, 256, 0, stream>>>(emb, Wx, bia, P);
    rnn_scan<<<BATCH / 8, 256, 0, stream>>>(x, P, Wh, Wd, bd, out);
}